// Round 7
// baseline (3878.315 us; speedup 1.0000x reference)
//
#include <hip/hip_runtime.h>

#define NF 32
#define HDIM 256
#define SLEN 256
#define BATCH 1024

typedef float f32x4 __attribute__((ext_vector_type(4)));
typedef __bf16 bf16x8 __attribute__((ext_vector_type(8)));
typedef unsigned int u32x4 __attribute__((ext_vector_type(4)));
typedef unsigned short u16;

#define MFMA __builtin_amdgcn_mfma_f32_16x16x32_bf16

// ---- ws layout ----
// uint4 slots [0, 672KB): packed MFMA B-fragments
// bytes [1MB, 5MB):  Wt bf16 [32 f][65536 k], k = s*256 + h   (W_sig transposed)
// bytes [8MB, 40MB): hst bf16 [1024 b][256 s][256 h]
#define WHH_O 0       // 64 j * 8 t * 64 l  = 32768 slots
#define WIH_O 32768   // 64 j * 64 l        =  4096
#define WOUT_O 36864  //  2 j * 8 t * 64 l  =  1024
#define WLAT_O 37888  // 32 j * 2 t * 64 l  =  4096
#define PREP1_N 41984
#define WT_BYTE (1u << 20)
#define HST_BYTE (8u << 20)

__device__ __forceinline__ u16 f2bf(float x) {
  union { float f; unsigned int u; } v; v.f = x;
  return (u16)((v.u + 0x7FFFu + ((v.u >> 16) & 1u)) >> 16);  // RNE
}
__device__ __forceinline__ unsigned int pk2(float a, float b) {
  return (unsigned int)f2bf(a) | ((unsigned int)f2bf(b) << 16);
}
__device__ __forceinline__ float sigf(float x) {
  return __fdividef(1.0f, 1.0f + __expf(-x));
}
__device__ __forceinline__ float tanhf_(float x) {
  return 1.0f - __fdividef(2.0f, __expf(2.0f * x) + 1.0f);
}

// Pack W_hh / W_ih / W_out / W_lat into MFMA B-fragment order:
// slot(j,t,l) element e = W[n=j*16+(l&15)][k=t*32+8*(l>>4)+e]
__global__ void prep_weights(const float* __restrict__ Whh, const float* __restrict__ Wih,
                             const float* __restrict__ Wout, const float* __restrict__ Wlat,
                             uint4* __restrict__ ws) {
  int i = blockIdx.x * 256 + threadIdx.x;
  if (i >= PREP1_N) return;
  int l = i & 63;
  int c16 = l & 15, g4 = l >> 4;
  const float* src;
  if (i < WIH_O) {                       // W_hh: rowlen 256
    int t = (i >> 6) & 7, j = i >> 9;
    src = Whh + (j * 16 + c16) * 256 + t * 32 + 8 * g4;
  } else if (i < WOUT_O) {               // W_ih: rowlen 32, single k-tile
    int ii = i - WIH_O;
    int j = ii >> 6;
    src = Wih + (j * 16 + c16) * 32 + 8 * g4;
  } else if (i < WLAT_O) {               // W_out: rowlen 256
    int ii = i - WOUT_O;
    int t = (ii >> 6) & 7, j = ii >> 9;
    src = Wout + (j * 16 + c16) * 256 + t * 32 + 8 * g4;
  } else {                               // W_lat: rowlen 64, 2 k-tiles
    int ii = i - WLAT_O;
    int t = (ii >> 6) & 1, j = ii >> 7;
    src = Wlat + (j * 16 + c16) * 64 + t * 32 + 8 * g4;
  }
  uint4 P;
  P.x = pk2(src[0], src[1]);
  P.y = pk2(src[2], src[3]);
  P.z = pk2(src[4], src[5]);
  P.w = pk2(src[6], src[7]);
  ws[i] = P;
}

// Transpose W_sig [32 f][h*256+s] (f32) -> Wt [32 f][s*256+h] (bf16).
__global__ void prep_wt(const float* __restrict__ Wsig, unsigned short* __restrict__ Wt) {
  __shared__ float tile[32][257];
  int f = blockIdx.x >> 3, hb = blockIdx.x & 7;
  int tid = threadIdx.x;  // 256
  const float* src = Wsig + f * (HDIM * SLEN) + hb * 32 * 256;
#pragma unroll
  for (int i = 0; i < 32; ++i) tile[i][tid] = src[i * 256 + tid];
  __syncthreads();
  int s = tid;
  unsigned short tmp[32];
#pragma unroll
  for (int h = 0; h < 32; ++h) tmp[h] = f2bf(tile[h][s]);
  uint4* dst = (uint4*)(Wt + f * 65536 + s * 256 + hb * 32);
  const uint4* tsrc = (const uint4*)tmp;
#pragma unroll
  for (int j = 0; j < 4; ++j) dst[j] = tsrc[j];
}

// Persistent LSTM scan: 64 WGs x 16 batch rows, 16 waves (1024 thr), 256 steps.
// j-split 4 tiles/wave: wave w owns j in {w, 16+w, 32+w, 48+w} so i/f/g/o for
// h-col (w*16+c16) are lane-local. 4 waves/SIMD hide L2/LDS latency.
__global__ __launch_bounds__(1024) void lstm_scan(
    const float* __restrict__ z, const float* __restrict__ b_lat,
    const float* __restrict__ b_ih, const float* __restrict__ b_hh,
    const float* __restrict__ b_out,
    const uint4* __restrict__ ws, unsigned short* __restrict__ hst,
    float* __restrict__ out) {
  __shared__ __align__(16) u16 hbuf[2][16][256];          // 16KB (swizzled)
  __shared__ __align__(16) u16 thbuf[16][256];            // 8KB (swizzled; z-stage at init)
  __shared__ __align__(16) u16 xbuf[2][16][32];           // 2KB
  __shared__ __align__(16) float mubuf[16][16][32];       // 32KB

  const int tid = threadIdx.x, w = tid >> 6, l = tid & 63;
  const int c16 = l & 15, g4 = l >> 4, r0 = g4 * 4;
  const int wg = blockIdx.x;
  const int swz = (c16 & 7) << 3;

  // per-wave persistent regs: W_ih frags + gate bias for the 4 owned j-tiles
  bf16x8 wih[4];
  float biasv[4];
#pragma unroll
  for (int gi = 0; gi < 4; ++gi) {
    int j = gi * 16 + w;
    wih[gi] = *reinterpret_cast<const bf16x8*>(ws + WIH_O + j * 64 + l);
    int n = j * 16 + c16;
    biasv[gi] = b_ih[n] + b_hh[n];
  }
  // x-waves (14,15): W_out frags in regs
  const int jn = w - 14;
  bf16x8 wo[8];
  float bo = 0.f;
  if (w >= 14) {
#pragma unroll
    for (int t = 0; t < 8; ++t)
      wo[t] = *reinterpret_cast<const bf16x8*>(ws + WOUT_O + (jn * 8 + t) * 64 + l);
    bo = b_out[jn * 16 + c16];
  }

  // ---- init: z -> thbuf staging (cols 0..63, unswizzled), x0 = 0 ----
  thbuf[tid >> 6][tid & 63] = f2bf(z[(wg * 16 + (tid >> 6)) * 64 + (tid & 63)]);
  if (tid < 512) xbuf[0][tid >> 5][tid & 31] = 0;
  __syncthreads();

  // hc = z @ W_lat^T + b_lat : wave w computes h-tile j=w and c-tile j=16+w
  float cst[4];
  {
    bf16x8 za0 = *reinterpret_cast<const bf16x8*>(&thbuf[c16][8 * g4]);
    bf16x8 za1 = *reinterpret_cast<const bf16x8*>(&thbuf[c16][32 + 8 * g4]);
    float blh = b_lat[w * 16 + c16];
    float blc = b_lat[256 + w * 16 + c16];
    f32x4 ah = {blh, blh, blh, blh}, ac = {blc, blc, blc, blc};
    ah = MFMA(za0, *reinterpret_cast<const bf16x8*>(ws + WLAT_O + (w * 2 + 0) * 64 + l), ah, 0, 0, 0);
    ah = MFMA(za1, *reinterpret_cast<const bf16x8*>(ws + WLAT_O + (w * 2 + 1) * 64 + l), ah, 0, 0, 0);
    ac = MFMA(za0, *reinterpret_cast<const bf16x8*>(ws + WLAT_O + ((16 + w) * 2 + 0) * 64 + l), ac, 0, 0, 0);
    ac = MFMA(za1, *reinterpret_cast<const bf16x8*>(ws + WLAT_O + ((16 + w) * 2 + 1) * 64 + l), ac, 0, 0, 0);
    const int hc = w * 16 + c16;
#pragma unroll
    for (int v = 0; v < 4; ++v) {
      cst[v] = ac[v];
      int rr = r0 + v;
      hbuf[0][rr][hc ^ ((rr & 7) << 3)] = f2bf(ah[v]);
    }
  }
  __syncthreads();

  // ---- the scan ----
  for (int s = 0; s < SLEN; ++s) {
    const int pb = s & 1;
    // phase 1: gates for the 4 owned j-tiles (9 MFMA each)
    bf16x8 afr[8];
#pragma unroll
    for (int kt = 0; kt < 8; ++kt)
      afr[kt] = *reinterpret_cast<const bf16x8*>(&hbuf[pb][c16][(kt * 32 + 8 * g4) ^ swz]);
    bf16x8 xfr = *reinterpret_cast<const bf16x8*>(&xbuf[pb][c16][8 * g4]);
    f32x4 acc[4];
#pragma unroll
    for (int gi = 0; gi < 4; ++gi) {
      f32x4 a = {biasv[gi], biasv[gi], biasv[gi], biasv[gi]};
      a = MFMA(xfr, wih[gi], a, 0, 0, 0);
      const uint4* bp = ws + WHH_O + ((gi * 16 + w) * 8) * 64 + l;
#pragma unroll
      for (int kt = 0; kt < 8; ++kt)
        a = MFMA(afr[kt], *reinterpret_cast<const bf16x8*>(bp + kt * 64), a, 0, 0, 0);
      acc[gi] = a;
    }
    // elementwise: lane owns 4 batch rows x 1 h-col (hc)
    {
      const int hc = w * 16 + c16;
#pragma unroll
      for (int v = 0; v < 4; ++v) {
        float iv = acc[0][v];
        float fv = acc[1][v];
        float gv = acc[2][v];
        float ov = acc[3][v];
        float cc = sigf(fv) * cst[v] + sigf(iv) * tanhf_(gv);
        cst[v] = cc;
        float hh = sigf(ov) * tanhf_(cc);
        float th = tanhf_(hh);
        int rr = r0 + v;
        int sc = hc ^ ((rr & 7) << 3);
        hbuf[pb ^ 1][rr][sc] = f2bf(hh);
        thbuf[rr][sc] = f2bf(th);
      }
    }
    __syncthreads();  // B1
    // phase 3: waves 14-15: x_{s+1} = tanh(h_{s+1}) @ W_out^T -> xbuf + mubuf;
    //          waves 0-7:   h_{s+1} -> hst (coalesced bf16)
    if (w >= 14) {
      f32x4 xacc = {bo, bo, bo, bo};
#pragma unroll
      for (int t = 0; t < 8; ++t) {
        bf16x8 ta = *reinterpret_cast<const bf16x8*>(&thbuf[c16][(t * 32 + 8 * g4) ^ swz]);
        xacc = MFMA(ta, wo[t], xacc, 0, 0, 0);
      }
      const int f = jn * 16 + c16;
      const int sw = s & 15;
#pragma unroll
      for (int v = 0; v < 4; ++v) {
        int rr = r0 + v;
        xbuf[pb ^ 1][rr][f] = f2bf(xacc[v]);
        mubuf[sw][rr][f] = xacc[v];
      }
    } else if (w < 8) {
      int r = tid >> 5;
      int h0 = (tid & 31) * 8;
      uint4 d = *reinterpret_cast<const uint4*>(&hbuf[pb ^ 1][r][h0 ^ ((r & 7) << 3)]);
      *reinterpret_cast<uint4*>(hst + ((wg * 16 + r) << 16) + (s << 8) + h0) = d;
    }
    __syncthreads();  // B2
    if ((s & 15) == 15 && tid < 512) {
      // flush 16 steps of mu: thread (b,f) writes 16 consecutive s -> 64B line
      int b = tid >> 5, f = tid & 31;
      float* dst = out + ((wg * 16 + b) << 13) + (f << 8) + (s - 15);
#pragma unroll
      for (int j4 = 0; j4 < 4; ++j4) {
        f32x4 vv;
#pragma unroll
        for (int jj = 0; jj < 4; ++jj) vv[jj] = mubuf[j4 * 4 + jj][b][f];
        *reinterpret_cast<f32x4*>(dst + j4 * 4) = vv;
      }
      // safe: next mubuf write happens after B1 of step s+1
    }
  }
}

// sigma = softplus(hs_flat @ W_sig^T + b_sig)
// 256 WGs x 4 batch rows; each wave owns a 8192-wide k-chunk; LDS reduce.
__global__ __launch_bounds__(512) void sigma_gemm(
    const unsigned short* __restrict__ hst, const unsigned short* __restrict__ Wt,
    const float* __restrict__ b_sig, float* __restrict__ out) {
  __shared__ float sred[8][16][32];  // 16KB
  const int tid = threadIdx.x;
  const int w = tid >> 6;
  const int l = tid & 63;
  const int c16 = l & 15;
  const int g4 = l >> 4;
  const int wg = blockIdx.x;

  const unsigned short* ap =
      hst + (((wg << 2) + (c16 & 3)) << 16) + ((w * 32) << 8) + (g4 << 3);
  const unsigned short* bp0 = Wt + (c16 << 16) + ((w * 32) << 8) + (g4 << 3);
  const unsigned short* bp1 = Wt + ((16 + c16) << 16) + ((w * 32) << 8) + (g4 << 3);

  f32x4 a0 = {0.f, 0.f, 0.f, 0.f}, a1 = {0.f, 0.f, 0.f, 0.f};
#pragma unroll 8
  for (int kk = 0; kk < 256; ++kk) {
    int off = ((kk >> 3) << 8) + ((kk & 7) << 5);
    bf16x8 av = *reinterpret_cast<const bf16x8*>(ap + off);
    a0 = MFMA(av, *reinterpret_cast<const bf16x8*>(bp0 + off), a0, 0, 0, 0);
    a1 = MFMA(av, *reinterpret_cast<const bf16x8*>(bp1 + off), a1, 0, 0, 0);
  }
#pragma unroll
  for (int v = 0; v < 4; ++v) {
    sred[w][g4 * 4 + v][c16] = a0[v];
    sred[w][g4 * 4 + v][16 + c16] = a1[v];
  }
  __syncthreads();
  int b = tid >> 5, f = tid & 31;
  if (b < 4) {
    float acc = b_sig[f];
#pragma unroll
    for (int ww = 0; ww < 8; ++ww) acc += sred[ww][b][f];
    float sp = fmaxf(acc, 0.0f) + log1pf(__expf(-fabsf(acc)));
    out[BATCH * NF * SLEN + ((wg << 2) + b) * NF + f] = sp;
  }
}

extern "C" void kernel_launch(void* const* d_in, const int* in_sizes, int n_in,
                              void* d_out, int out_size, void* d_ws, size_t ws_size,
                              hipStream_t stream) {
  (void)in_sizes; (void)n_in; (void)out_size; (void)ws_size;
  const float* z     = (const float*)d_in[0];
  const float* W_lat = (const float*)d_in[1];
  const float* b_lat = (const float*)d_in[2];
  const float* W_ih  = (const float*)d_in[3];
  const float* b_ih  = (const float*)d_in[4];
  const float* W_hh  = (const float*)d_in[5];
  const float* b_hh  = (const float*)d_in[6];
  const float* W_out = (const float*)d_in[7];
  const float* b_out = (const float*)d_in[8];
  const float* W_sig = (const float*)d_in[9];
  const float* b_sig = (const float*)d_in[10];
  char* wsb = (char*)d_ws;
  uint4* ws = (uint4*)wsb;
  unsigned short* Wt  = (unsigned short*)(wsb + WT_BYTE);
  unsigned short* hst = (unsigned short*)(wsb + HST_BYTE);
  float* out = (float*)d_out;

  prep_weights<<<(PREP1_N + 255) / 256, 256, 0, stream>>>(W_hh, W_ih, W_out, W_lat, ws);
  prep_wt<<<256, 256, 0, stream>>>(W_sig, Wt);
  lstm_scan<<<64, 1024, 0, stream>>>(z, b_lat, b_ih, b_hh, b_out, ws, hst, out);
  sigma_gemm<<<256, 512, 0, stream>>>(hst, Wt, b_sig, out);
}

// Round 8
// 3102.283 us; speedup vs baseline: 1.2501x; 1.2501x over previous
//
#include <hip/hip_runtime.h>

#define NF 32
#define HDIM 256
#define SLEN 256
#define BATCH 1024

typedef float f32x4 __attribute__((ext_vector_type(4)));
typedef __bf16 bf16x8 __attribute__((ext_vector_type(8)));
typedef unsigned int u32x4 __attribute__((ext_vector_type(4)));
typedef unsigned short u16;

#define MFMA __builtin_amdgcn_mfma_f32_16x16x32_bf16

// ---- ws layout ----
// uint4 slots [0, 672KB): packed MFMA B-fragments
// bytes [1MB, 5MB):  Wt bf16 [32 f][65536 k], k = s*256 + h   (W_sig transposed)
// bytes [8MB, 40MB): hst bf16 [1024 b][256 s][256 h]
#define WHH_O 0       // 64 j * 8 t * 64 l  = 32768 slots
#define WIH_O 32768   // 64 j * 64 l        =  4096
#define WOUT_O 36864  //  2 j * 8 t * 64 l  =  1024
#define WLAT_O 37888  // 32 j * 2 t * 64 l  =  4096
#define PREP1_N 41984
#define WT_BYTE (1u << 20)
#define HST_BYTE (8u << 20)

__device__ __forceinline__ u16 f2bf(float x) {
  __bf16 b = (__bf16)x;                 // RNE; compiler pairs into v_cvt_pk_bf16_f32
  return __builtin_bit_cast(u16, b);
}
__device__ __forceinline__ unsigned int pk2(float a, float b) {
  return (unsigned int)f2bf(a) | ((unsigned int)f2bf(b) << 16);
}
__device__ __forceinline__ float sigf(float x) {
  return __fdividef(1.0f, 1.0f + __expf(-x));
}
__device__ __forceinline__ float tanhf_(float x) {
  return 1.0f - __fdividef(2.0f, __expf(2.0f * x) + 1.0f);
}

// Pack W_hh / W_ih / W_out / W_lat into MFMA B-fragment order:
// slot(j,t,l) element e = W[n=j*16+(l&15)][k=t*32+8*(l>>4)+e]
__global__ void prep_weights(const float* __restrict__ Whh, const float* __restrict__ Wih,
                             const float* __restrict__ Wout, const float* __restrict__ Wlat,
                             uint4* __restrict__ ws) {
  int i = blockIdx.x * 256 + threadIdx.x;
  if (i >= PREP1_N) return;
  int l = i & 63;
  int c16 = l & 15, g4 = l >> 4;
  const float* src;
  if (i < WIH_O) {                       // W_hh: rowlen 256
    int t = (i >> 6) & 7, j = i >> 9;
    src = Whh + (j * 16 + c16) * 256 + t * 32 + 8 * g4;
  } else if (i < WOUT_O) {               // W_ih: rowlen 32, single k-tile
    int ii = i - WIH_O;
    int j = ii >> 6;
    src = Wih + (j * 16 + c16) * 32 + 8 * g4;
  } else if (i < WLAT_O) {               // W_out: rowlen 256
    int ii = i - WOUT_O;
    int t = (ii >> 6) & 7, j = ii >> 9;
    src = Wout + (j * 16 + c16) * 256 + t * 32 + 8 * g4;
  } else {                               // W_lat: rowlen 64, 2 k-tiles
    int ii = i - WLAT_O;
    int t = (ii >> 6) & 1, j = ii >> 7;
    src = Wlat + (j * 16 + c16) * 64 + t * 32 + 8 * g4;
  }
  uint4 P;
  P.x = pk2(src[0], src[1]);
  P.y = pk2(src[2], src[3]);
  P.z = pk2(src[4], src[5]);
  P.w = pk2(src[6], src[7]);
  ws[i] = P;
}

// Transpose W_sig [32 f][h*256+s] (f32) -> Wt [32 f][s*256+h] (bf16).
__global__ void prep_wt(const float* __restrict__ Wsig, unsigned short* __restrict__ Wt) {
  __shared__ float tile[32][257];
  int f = blockIdx.x >> 3, hb = blockIdx.x & 7;
  int tid = threadIdx.x;  // 256
  const float* src = Wsig + f * (HDIM * SLEN) + hb * 32 * 256;
#pragma unroll
  for (int i = 0; i < 32; ++i) tile[i][tid] = src[i * 256 + tid];
  __syncthreads();
  int s = tid;
  unsigned short tmp[32];
#pragma unroll
  for (int h = 0; h < 32; ++h) tmp[h] = f2bf(tile[h][s]);
  uint4* dst = (uint4*)(Wt + f * 65536 + s * 256 + hb * 32);
  const uint4* tsrc = (const uint4*)tmp;
#pragma unroll
  for (int j = 0; j < 4; ++j) dst[j] = tsrc[j];
}

// Persistent LSTM scan: 64 WGs x 16 batch rows, 16 waves, 256 steps.
// Wave w owns j in {w,16+w,32+w,48+w} (gi = gate index) so i/f/g/o are
// lane-local. W_hh kt0..2 truly pinned in VGPRs (in-loop asm keep-alive),
// kt3..7 streamed from L2; W_ih + W_out LDS-resident.
__global__ __launch_bounds__(1024, 4) void lstm_scan(
    const float* __restrict__ z, const float* __restrict__ b_lat,
    const float* __restrict__ b_ih, const float* __restrict__ b_hh,
    const float* __restrict__ b_out,
    const uint4* __restrict__ ws, unsigned short* __restrict__ hst,
    float* __restrict__ out) {
  __shared__ __align__(16) uint4 wihl[4096];              // 64KB W_ih frags
  __shared__ __align__(16) uint4 woutb[1024];             // 16KB W_out frags
  __shared__ __align__(16) u16 hbuf[2][16][256];          // 16KB (swizzled)
  __shared__ __align__(16) u16 thbuf[16][256];            // 8KB (swizzled; z-stage)
  __shared__ __align__(16) u16 xbuf[2][16][32];           // 2KB
  __shared__ __align__(16) float mubuf[16][16][32];       // 32KB

  const int tid = threadIdx.x, w = tid >> 6, l = tid & 63;
  const int c16 = l & 15, g4 = l >> 4, r0 = g4 * 4;
  const int wg = blockIdx.x;
  const int swz = (c16 & 7) << 3;

  // one-time LDS fills
  for (int i = tid; i < 4096; i += 1024) wihl[i] = ws[WIH_O + i];
  for (int i = tid; i < 1024; i += 1024) woutb[i] = ws[WOUT_O + i];

  // pinned W_hh kt0..2 for the 4 owned j-tiles (48 VGPR)
  u32x4 wp[4][3];
#pragma unroll
  for (int gi = 0; gi < 4; ++gi)
#pragma unroll
    for (int kk = 0; kk < 3; ++kk)
      wp[gi][kk] = __builtin_bit_cast(u32x4, ws[WHH_O + ((gi * 16 + w) * 8 + kk) * 64 + l]);

  // streamed bases at kt=4 (imm offsets -1024..+3072 cover kt3..7)
  const uint4* bs[4];
#pragma unroll
  for (int gi = 0; gi < 4; ++gi) bs[gi] = ws + WHH_O + ((gi * 16 + w) * 8 + 4) * 64 + l;

  float biasv[4];
#pragma unroll
  for (int gi = 0; gi < 4; ++gi) {
    int n = (gi * 16 + w) * 16 + c16;
    biasv[gi] = b_ih[n] + b_hh[n];
  }
  const int jn = w - 14;
  float bo = (w >= 14) ? b_out[jn * 16 + c16] : 0.f;

  // ---- init: z -> thbuf staging (cols 0..63, unswizzled), x0 = 0 ----
  thbuf[tid >> 6][tid & 63] = f2bf(z[(wg * 16 + (tid >> 6)) * 64 + (tid & 63)]);
  if (tid < 512) xbuf[0][tid >> 5][tid & 31] = 0;
  __syncthreads();

  // hc = z @ W_lat^T + b_lat : wave w computes h-tile j=w, c-tile j=16+w
  float cst[4];
  {
    bf16x8 za0 = *reinterpret_cast<const bf16x8*>(&thbuf[c16][8 * g4]);
    bf16x8 za1 = *reinterpret_cast<const bf16x8*>(&thbuf[c16][32 + 8 * g4]);
    float blh = b_lat[w * 16 + c16];
    float blc = b_lat[256 + w * 16 + c16];
    f32x4 ah = {blh, blh, blh, blh}, ac = {blc, blc, blc, blc};
    ah = MFMA(za0, *reinterpret_cast<const bf16x8*>(ws + WLAT_O + (w * 2 + 0) * 64 + l), ah, 0, 0, 0);
    ah = MFMA(za1, *reinterpret_cast<const bf16x8*>(ws + WLAT_O + (w * 2 + 1) * 64 + l), ah, 0, 0, 0);
    ac = MFMA(za0, *reinterpret_cast<const bf16x8*>(ws + WLAT_O + ((16 + w) * 2 + 0) * 64 + l), ac, 0, 0, 0);
    ac = MFMA(za1, *reinterpret_cast<const bf16x8*>(ws + WLAT_O + ((16 + w) * 2 + 1) * 64 + l), ac, 0, 0, 0);
    const int hc = w * 16 + c16;
#pragma unroll
    for (int v = 0; v < 4; ++v) {
      cst[v] = ac[v];
      int rr = r0 + v;
      hbuf[0][rr][hc ^ ((rr & 7) << 3)] = f2bf(ah[v]);
    }
  }
  __syncthreads();

  // ---- the scan ----
  for (int s = 0; s < SLEN; ++s) {
    const int pb = s & 1;
    // phase 1: gates. kt-outer so afr liveness stays low; streamed kt3..7
    // loads get hoisted by the scheduler under the pinned-kt MFMAs.
    f32x4 acc[4];
#pragma unroll
    for (int gi = 0; gi < 4; ++gi)
      acc[gi] = (f32x4){biasv[gi], biasv[gi], biasv[gi], biasv[gi]};
#pragma unroll
    for (int kt = 0; kt < 8; ++kt) {
      bf16x8 afr = *reinterpret_cast<const bf16x8*>(&hbuf[pb][c16][(kt * 32 + 8 * g4) ^ swz]);
      if (kt < 3) {
#pragma unroll
        for (int gi = 0; gi < 4; ++gi)
          acc[gi] = MFMA(afr, __builtin_bit_cast(bf16x8, wp[gi][kt]), acc[gi], 0, 0, 0);
      } else {
#pragma unroll
        for (int gi = 0; gi < 4; ++gi)
          acc[gi] = MFMA(afr, *reinterpret_cast<const bf16x8*>(bs[gi] + (kt - 4) * 64), acc[gi], 0, 0, 0);
      }
    }
    {
      bf16x8 xfr = *reinterpret_cast<const bf16x8*>(&xbuf[pb][c16][8 * g4]);
#pragma unroll
      for (int gi = 0; gi < 4; ++gi)
        acc[gi] = MFMA(xfr, *reinterpret_cast<const bf16x8*>(&wihl[(gi * 16 + w) * 64 + l]), acc[gi], 0, 0, 0);
    }
    // elementwise: lane owns 4 batch rows x 1 h-col
    {
      const int hc = w * 16 + c16;
#pragma unroll
      for (int v = 0; v < 4; ++v) {
        float iv = acc[0][v];
        float fv = acc[1][v];
        float gv = acc[2][v];
        float ov = acc[3][v];
        float cc = sigf(fv) * cst[v] + sigf(iv) * tanhf_(gv);
        cst[v] = cc;
        float hh = sigf(ov) * tanhf_(cc);
        float th = tanhf_(hh);
        int rr = r0 + v;
        int sc = hc ^ ((rr & 7) << 3);
        hbuf[pb ^ 1][rr][sc] = f2bf(hh);
        thbuf[rr][sc] = f2bf(th);
      }
    }
    __syncthreads();  // B1
    // phase 3: waves 14-15: x_{s+1} = tanh(h_{s+1}) @ W_out^T -> xbuf + mubuf;
    //          waves 0-7:   h_{s+1} -> hst (coalesced bf16)
    if (w >= 14) {
      f32x4 xacc = {bo, bo, bo, bo};
#pragma unroll
      for (int t = 0; t < 8; ++t) {
        bf16x8 ta = *reinterpret_cast<const bf16x8*>(&thbuf[c16][(t * 32 + 8 * g4) ^ swz]);
        xacc = MFMA(ta, *reinterpret_cast<const bf16x8*>(&woutb[(jn * 8 + t) * 64 + l]), xacc, 0, 0, 0);
      }
      const int f = jn * 16 + c16;
      const int sw = s & 15;
#pragma unroll
      for (int v = 0; v < 4; ++v) {
        int rr = r0 + v;
        xbuf[pb ^ 1][rr][f] = f2bf(xacc[v]);
        mubuf[sw][rr][f] = xacc[v];
      }
    } else if (w < 8) {
      int r = tid >> 5;
      int h0 = (tid & 31) * 8;
      uint4 d = *reinterpret_cast<const uint4*>(&hbuf[pb ^ 1][r][h0 ^ ((r & 7) << 3)]);
      *reinterpret_cast<uint4*>(hst + ((wg * 16 + r) << 16) + (s << 8) + h0) = d;
    }
    __syncthreads();  // B2
    if ((s & 15) == 15 && tid < 512) {
      // flush 16 steps of mu: thread (b,f) writes 16 consecutive s -> 64B line
      int b = tid >> 5, f = tid & 31;
      float* dst = out + ((wg * 16 + b) << 13) + (f << 8) + (s - 15);
#pragma unroll
      for (int j4 = 0; j4 < 4; ++j4) {
        f32x4 vv;
#pragma unroll
        for (int jj = 0; jj < 4; ++jj) vv[jj] = mubuf[j4 * 4 + jj][b][f];
        *reinterpret_cast<f32x4*>(dst + j4 * 4) = vv;
      }
      // safe: next mubuf write happens after B1 of step s+1
    }
    // keep-alive: loop-carried dep forces wp to stay in VGPRs (no remat)
#pragma unroll
    for (int gi = 0; gi < 4; ++gi)
#pragma unroll
      for (int kk = 0; kk < 3; ++kk)
        asm volatile("" : "+v"(wp[gi][kk]));
  }
}

// sigma = softplus(hs_flat @ W_sig^T + b_sig)
// 256 WGs x 4 batch rows; each wave owns a 8192-wide k-chunk; LDS reduce.
__global__ __launch_bounds__(512) void sigma_gemm(
    const unsigned short* __restrict__ hst, const unsigned short* __restrict__ Wt,
    const float* __restrict__ b_sig, float* __restrict__ out) {
  __shared__ float sred[8][16][32];  // 16KB
  const int tid = threadIdx.x;
  const int w = tid >> 6;
  const int l = tid & 63;
  const int c16 = l & 15;
  const int g4 = l >> 4;
  const int wg = blockIdx.x;

  const unsigned short* ap =
      hst + (((wg << 2) + (c16 & 3)) << 16) + ((w * 32) << 8) + (g4 << 3);
  const unsigned short* bp0 = Wt + (c16 << 16) + ((w * 32) << 8) + (g4 << 3);
  const unsigned short* bp1 = Wt + ((16 + c16) << 16) + ((w * 32) << 8) + (g4 << 3);

  f32x4 a0 = {0.f, 0.f, 0.f, 0.f}, a1 = {0.f, 0.f, 0.f, 0.f};
#pragma unroll 8
  for (int kk = 0; kk < 256; ++kk) {
    int off = ((kk >> 3) << 8) + ((kk & 7) << 5);
    bf16x8 av = *reinterpret_cast<const bf16x8*>(ap + off);
    a0 = MFMA(av, *reinterpret_cast<const bf16x8*>(bp0 + off), a0, 0, 0, 0);
    a1 = MFMA(av, *reinterpret_cast<const bf16x8*>(bp1 + off), a1, 0, 0, 0);
  }
#pragma unroll
  for (int v = 0; v < 4; ++v) {
    sred[w][g4 * 4 + v][c16] = a0[v];
    sred[w][g4 * 4 + v][16 + c16] = a1[v];
  }
  __syncthreads();
  int b = tid >> 5, f = tid & 31;
  if (b < 4) {
    float acc = b_sig[f];
#pragma unroll
    for (int ww = 0; ww < 8; ++ww) acc += sred[ww][b][f];
    float sp = fmaxf(acc, 0.0f) + log1pf(__expf(-fabsf(acc)));
    out[BATCH * NF * SLEN + ((wg << 2) + b) * NF + f] = sp;
  }
}

extern "C" void kernel_launch(void* const* d_in, const int* in_sizes, int n_in,
                              void* d_out, int out_size, void* d_ws, size_t ws_size,
                              hipStream_t stream) {
  (void)in_sizes; (void)n_in; (void)out_size; (void)ws_size;
  const float* z     = (const float*)d_in[0];
  const float* W_lat = (const float*)d_in[1];
  const float* b_lat = (const float*)d_in[2];
  const float* W_ih  = (const float*)d_in[3];
  const float* b_ih  = (const float*)d_in[4];
  const float* W_hh  = (const float*)d_in[5];
  const float* b_hh  = (const float*)d_in[6];
  const float* W_out = (const float*)d_in[7];
  const float* b_out = (const float*)d_in[8];
  const float* W_sig = (const float*)d_in[9];
  const float* b_sig = (const float*)d_in[10];
  char* wsb = (char*)d_ws;
  uint4* ws = (uint4*)wsb;
  unsigned short* Wt  = (unsigned short*)(wsb + WT_BYTE);
  unsigned short* hst = (unsigned short*)(wsb + HST_BYTE);
  float* out = (float*)d_out;

  prep_weights<<<(PREP1_N + 255) / 256, 256, 0, stream>>>(W_hh, W_ih, W_out, W_lat, ws);
  prep_wt<<<256, 256, 0, stream>>>(W_sig, Wt);
  lstm_scan<<<64, 1024, 0, stream>>>(z, b_lat, b_ih, b_hh, b_out, ws, hst, out);
  sigma_gemm<<<256, 512, 0, stream>>>(hst, Wt, b_sig, out);
}